// Round 1
// baseline (214.833 us; speedup 1.0000x reference)
//
#include <hip/hip_runtime.h>
#include <hip/hip_bf16.h>

using bf = __bf16;
typedef __attribute__((ext_vector_type(8))) __bf16 bf16x8;
typedef __attribute__((ext_vector_type(4))) float f32x4;

#define M_TOT 4096
#define D_EMB 512
#define F_FFN 2048

// ---------- prep: phi features (rank-16 factorization of the gram) ----------
// phi[i][m] = prod_k ( bit_k(m) ? sin(f_ik/2) : cos(f_ik/2) ), padded to 32 with 0
__global__ __launch_bounds__(256) void k_phi(const float* __restrict__ x, bf* __restrict__ phib) {
  int i = blockIdx.x * 256 + threadIdx.x;  // 0..4095
  float c[4], s[4];
#pragma unroll
  for (int k = 0; k < 4; ++k) {
    float f = x[(size_t)i * D_EMB + k] * 0.5f;
    sincosf(f, &s[k], &c[k]);
  }
#pragma unroll
  for (int m = 0; m < 16; ++m) {
    float p = 1.0f;
#pragma unroll
    for (int k = 0; k < 4; ++k) p *= ((m >> k) & 1) ? s[k] : c[k];
    phib[(size_t)i * 32 + m] = (bf)p;
  }
#pragma unroll
  for (int m = 16; m < 32; ++m) phib[(size_t)i * 32 + m] = (bf)0.0f;
}

// ---------- prep: transpose + convert f32 -> bf16 : out[c][r] = in[r][c] ----------
__global__ __launch_bounds__(256) void k_transpose_cvt(const float* __restrict__ in,
                                                       bf* __restrict__ out, int R, int C) {
  __shared__ float tile[32][33];
  int c0 = blockIdx.x * 32, r0 = blockIdx.y * 32;
  int tx = threadIdx.x, ty = threadIdx.y;  // 32 x 8
#pragma unroll
  for (int i = 0; i < 32; i += 8)
    tile[ty + i][tx] = in[(size_t)(r0 + ty + i) * C + c0 + tx];
  __syncthreads();
#pragma unroll
  for (int i = 0; i < 32; i += 8)
    out[(size_t)(c0 + ty + i) * R + r0 + tx] = (bf)tile[tx][ty + i];
}

// XOR swizzle for LDS tiles with 128-byte rows (8 x 16B chunks): spreads the
// 16-lane stride-128B fragment reads across 8 bank groups (G4 fix).
__device__ __forceinline__ int swz128(int row, int byteInRow) {
  return row * 128 + (byteInRow ^ ((row & 7) << 4));
}

// ---------- fused: out = |Phi Phi^T| @ flat ----------
// grid (M/64, D/128), 256 threads (4 waves). flatT is bf16 [D_EMB][M_TOT].
__global__ __launch_bounds__(256) void k_gram(const bf* __restrict__ phib,
                                              const bf* __restrict__ flatT,
                                              bf* __restrict__ outb) {
  __shared__ __align__(16) char sm[4096 + 4096 + 8192 + 16384];
  char* phiI = sm;            // [64][32] bf16, linear, 4KB
  char* phiJ = sm + 4096;     // [64][32] bf16, linear, 4KB
  char* sT   = sm + 8192;     // [64 m][64 j] bf16, swizzled, 8KB
  char* ft   = sm + 16384;    // [128 d][64 j] bf16, swizzled, 16KB

  const int tid = threadIdx.x;
  const int wave = tid >> 6, lane = tid & 63;
  const int lr = lane & 15, lg = lane >> 4;
  const int m0 = blockIdx.x * 64;
  const int n0 = blockIdx.y * 128;

  // stage phi_i rows m0..m0+63 once (64B/row -> 4 chunks, 256 chunks total)
  {
    int row = tid >> 2, ch = tid & 3;
    *(bf16x8*)(phiI + row * 64 + ch * 16) = *(const bf16x8*)(phib + (size_t)(m0 + row) * 32 + ch * 8);
  }

  f32x4 acc[8];
#pragma unroll
  for (int i = 0; i < 8; ++i) acc[i] = f32x4{0.f, 0.f, 0.f, 0.f};

  for (int jt = 0; jt < M_TOT / 64; ++jt) {
    const int j0 = jt * 64;
    __syncthreads();  // protect LDS from previous iteration's readers
    // stage phi_j (same pattern as phi_i)
    {
      int row = tid >> 2, ch = tid & 3;
      *(bf16x8*)(phiJ + row * 64 + ch * 16) = *(const bf16x8*)(phib + (size_t)(j0 + row) * 32 + ch * 8);
    }
    // stage ft: 128 rows (d) x 64 (j) bf16, 8 chunks/row -> 1024 chunks, 4/thread
#pragma unroll
    for (int i = 0; i < 4; ++i) {
      int idx = tid + i * 256;
      int row = idx >> 3, ch = idx & 7;
      *(bf16x8*)(ft + swz128(row, ch * 16)) =
          *(const bf16x8*)(flatT + (size_t)(n0 + row) * M_TOT + j0 + ch * 8);
    }
    __syncthreads();

    // S tile via MFMA: wave w -> S rows [w*16, w*16+16), 4 col frags; K=32 (16 real)
    {
      bf16x8 a = *(const bf16x8*)(phiI + (wave * 16 + lr) * 64 + lg * 16);
#pragma unroll
      for (int f = 0; f < 4; ++f) {
        bf16x8 b = *(const bf16x8*)(phiJ + (f * 16 + lr) * 64 + lg * 16);
        f32x4 sv = __builtin_amdgcn_mfma_f32_16x16x32_bf16(a, b, f32x4{0.f, 0.f, 0.f, 0.f}, 0, 0, 0);
#pragma unroll
        for (int r = 0; r < 4; ++r) {
          int srow = wave * 16 + lg * 4 + r;
          int scol = f * 16 + lr;
          *(bf*)(sT + swz128(srow, scol * 2)) = (bf)fabsf(sv[r]);
        }
      }
    }
    __syncthreads();

    // main MFMAs: out-tile rows [wave*16,+16), 8 col frags, K=64 in 2 steps
#pragma unroll
    for (int ks = 0; ks < 2; ++ks) {
      int arow = wave * 16 + lr;
      bf16x8 a = *(const bf16x8*)(sT + swz128(arow, (ks * 32 + lg * 8) * 2));
#pragma unroll
      for (int f = 0; f < 8; ++f) {
        int brow = f * 16 + lr;
        bf16x8 b = *(const bf16x8*)(ft + swz128(brow, (ks * 32 + lg * 8) * 2));
        acc[f] = __builtin_amdgcn_mfma_f32_16x16x32_bf16(a, b, acc[f], 0, 0, 0);
      }
    }
  }

  // epilogue: outb[m][d] bf16
#pragma unroll
  for (int f = 0; f < 8; ++f)
#pragma unroll
    for (int r = 0; r < 4; ++r) {
      int m = m0 + wave * 16 + lg * 4 + r;
      int d = n0 + f * 16 + lr;
      outb[(size_t)m * D_EMB + d] = (bf)acc[f][r];
    }
}

// ---------- generic bf16 GEMM: C = A[M][K] * B (given as BT[N][K]) + bias ----------
// RELU_BF16: out is bf16 with relu; else out is f32, no relu.
template <bool RELU_BF16>
__global__ __launch_bounds__(256) void k_gemm(const bf* __restrict__ A, const bf* __restrict__ BT,
                                              const float* __restrict__ bias, void* __restrict__ out,
                                              int M, int N, int K) {
  __shared__ __align__(16) char sm[8192 + 16384];
  char* aT = sm;         // [64 m][64 k] bf16 swizzled, 8KB
  char* bT = sm + 8192;  // [128 n][64 k] bf16 swizzled, 16KB

  const int tid = threadIdx.x;
  const int wave = tid >> 6, lane = tid & 63;
  const int lr = lane & 15, lg = lane >> 4;
  const int m0 = blockIdx.x * 64;
  const int n0 = blockIdx.y * 128;

  f32x4 acc[8];
#pragma unroll
  for (int i = 0; i < 8; ++i) acc[i] = f32x4{0.f, 0.f, 0.f, 0.f};

  for (int k0 = 0; k0 < K; k0 += 64) {
    __syncthreads();
    // stage A: 64 rows x 8 chunks = 512, 2/thread
#pragma unroll
    for (int i = 0; i < 2; ++i) {
      int idx = tid + i * 256;
      int row = idx >> 3, ch = idx & 7;
      *(bf16x8*)(aT + swz128(row, ch * 16)) =
          *(const bf16x8*)(A + (size_t)(m0 + row) * K + k0 + ch * 8);
    }
    // stage B: 128 rows x 8 chunks = 1024, 4/thread
#pragma unroll
    for (int i = 0; i < 4; ++i) {
      int idx = tid + i * 256;
      int row = idx >> 3, ch = idx & 7;
      *(bf16x8*)(bT + swz128(row, ch * 16)) =
          *(const bf16x8*)(BT + (size_t)(n0 + row) * K + k0 + ch * 8);
    }
    __syncthreads();
#pragma unroll
    for (int ks = 0; ks < 2; ++ks) {
      int arow = wave * 16 + lr;
      bf16x8 a = *(const bf16x8*)(aT + swz128(arow, (ks * 32 + lg * 8) * 2));
#pragma unroll
      for (int f = 0; f < 8; ++f) {
        int brow = f * 16 + lr;
        bf16x8 b = *(const bf16x8*)(bT + swz128(brow, (ks * 32 + lg * 8) * 2));
        acc[f] = __builtin_amdgcn_mfma_f32_16x16x32_bf16(a, b, acc[f], 0, 0, 0);
      }
    }
  }

#pragma unroll
  for (int f = 0; f < 8; ++f) {
    int n = n0 + f * 16 + lr;
    float bv = bias[n];
#pragma unroll
    for (int r = 0; r < 4; ++r) {
      int m = m0 + wave * 16 + lg * 4 + r;
      float v = acc[f][r] + bv;
      if (RELU_BF16) {
        v = v > 0.f ? v : 0.f;
        ((bf*)out)[(size_t)m * N + n] = (bf)v;
      } else {
        ((float*)out)[(size_t)m * N + n] = v;
      }
    }
  }
}

// ---------- workspace layout ----------
constexpr size_t OFF_PHI   = 0;                                      // 4096*32*2   = 256 KiB
constexpr size_t OFF_FLATT = OFF_PHI + (size_t)M_TOT * 32 * 2;       // 512*4096*2  = 4 MiB
constexpr size_t OFF_OUTB  = OFF_FLATT + (size_t)D_EMB * M_TOT * 2;  // 4096*512*2  = 4 MiB
constexpr size_t OFF_W1T   = OFF_OUTB + (size_t)M_TOT * D_EMB * 2;   // 2048*512*2  = 2 MiB
constexpr size_t OFF_W2T   = OFF_W1T + (size_t)F_FFN * D_EMB * 2;    // 512*2048*2  = 2 MiB
constexpr size_t OFF_HB    = OFF_W2T + (size_t)D_EMB * F_FFN * 2;    // 4096*2048*2 = 16 MiB

extern "C" void kernel_launch(void* const* d_in, const int* in_sizes, int n_in,
                              void* d_out, int out_size, void* d_ws, size_t ws_size,
                              hipStream_t stream) {
  const float* x  = (const float*)d_in[0];
  const float* W1 = (const float*)d_in[1];
  const float* b1 = (const float*)d_in[2];
  const float* W2 = (const float*)d_in[3];
  const float* b2 = (const float*)d_in[4];
  float* y = (float*)d_out;
  char* ws = (char*)d_ws;

  bf* phib  = (bf*)(ws + OFF_PHI);
  bf* flatT = (bf*)(ws + OFF_FLATT);
  bf* outb  = (bf*)(ws + OFF_OUTB);
  bf* w1T   = (bf*)(ws + OFF_W1T);
  bf* w2T   = (bf*)(ws + OFF_W2T);
  bf* hb    = (bf*)(ws + OFF_HB);

  // prep
  k_phi<<<M_TOT / 256, 256, 0, stream>>>(x, phib);
  k_transpose_cvt<<<dim3(D_EMB / 32, M_TOT / 32), dim3(32, 8), 0, stream>>>(x, flatT, M_TOT, D_EMB);
  k_transpose_cvt<<<dim3(F_FFN / 32, D_EMB / 32), dim3(32, 8), 0, stream>>>(W1, w1T, D_EMB, F_FFN);
  k_transpose_cvt<<<dim3(D_EMB / 32, F_FFN / 32), dim3(32, 8), 0, stream>>>(W2, w2T, F_FFN, D_EMB);

  // fused gram @ flat
  k_gram<<<dim3(M_TOT / 64, D_EMB / 128), 256, 0, stream>>>(phib, flatT, outb);

  // FFN
  k_gemm<true ><<<dim3(M_TOT / 64, F_FFN / 128), 256, 0, stream>>>(outb, w1T, b1, (void*)hb, M_TOT, F_FFN, D_EMB);
  k_gemm<false><<<dim3(M_TOT / 64, D_EMB / 128), 256, 0, stream>>>(hb, w2T, b2, (void*)y, M_TOT, D_EMB, F_FFN);
}

// Round 3
// 119.297 us; speedup vs baseline: 1.8008x; 1.8008x over previous
//
#include <hip/hip_runtime.h>
#include <hip/hip_bf16.h>
#include <stdint.h>

using bf = __bf16;
typedef __attribute__((ext_vector_type(8))) __bf16 bf16x8;
typedef __attribute__((ext_vector_type(4))) float f32x4;

#define M_TOT 4096
#define D_EMB 512
#define F_FFN 2048

// ---------- async global->LDS, 16B per lane ----------
__device__ __forceinline__ void gload_lds16(const void* g, void* l) {
  __builtin_amdgcn_global_load_lds(
      (const __attribute__((address_space(1))) uint32_t*)g,
      (__attribute__((address_space(3))) uint32_t*)l, 16, 0, 0);
}

// XOR swizzle for 128B-row LDS tiles (8 x 16B chunks per row).
__device__ __forceinline__ int swz128(int row, int byteInRow) {
  return row * 128 + (byteInRow ^ ((row & 7) << 4));
}
__device__ __forceinline__ bf16x8 ldfrag(const char* base, int row, int byteInRow) {
  return *(const bf16x8*)(base + swz128(row, byteInRow));
}

// Stage ROWS x 64 bf16 (128B rows) tile: linear LDS dest (gload_lds), INVERSE
// swizzle applied on the per-lane GLOBAL source chunk (rule #21 both-sides).
template <int ROWS>
__device__ __forceinline__ void stage_tile(const bf* gsrc, int ld, char* lbase, int wave, int lane) {
  const int rsub = lane >> 3, csub = lane & 7;
  const int sc = csub ^ rsub;  // source chunk for linear position csub of row rsub
#pragma unroll
  for (int i = 0; i < ROWS / 32; ++i) {
    int chunk = wave + i * 4;  // 4 waves, each wave-chunk = 1KB = 8 rows
    int row = chunk * 8 + rsub;
    gload_lds16((const char*)gsrc + (size_t)row * (size_t)(ld * 2) + sc * 16, lbase + chunk * 1024);
  }
}

// Stage 64 rows x 32 bf16 (source 64B rows) into a [64][128B] swizzled tile.
// Positions whose source chunk >=4 hold duplicate (never-read) data.
__device__ __forceinline__ void stage_phi(const bf* gsrc, char* lbase, int wave, int lane) {
  const int rsub = lane >> 3, csub = lane & 7;
  const int sc = (csub ^ rsub) & 3;
#pragma unroll
  for (int i = 0; i < 2; ++i) {
    int chunk = wave + i * 4;
    int row = chunk * 8 + rsub;
    gload_lds16((const char*)gsrc + (size_t)row * 64 + sc * 16, lbase + chunk * 1024);
  }
}

// ---------- prep: phi features (rank-16 factorization of the gram) ----------
__global__ __launch_bounds__(256) void k_phi(const float* __restrict__ x, bf* __restrict__ phib) {
  int i = blockIdx.x * 256 + threadIdx.x;
  float c[4], s[4];
#pragma unroll
  for (int k = 0; k < 4; ++k) {
    float f = x[(size_t)i * D_EMB + k] * 0.5f;
    sincosf(f, &s[k], &c[k]);
  }
#pragma unroll
  for (int m = 0; m < 16; ++m) {
    float p = 1.0f;
#pragma unroll
    for (int k = 0; k < 4; ++k) p *= ((m >> k) & 1) ? s[k] : c[k];
    phib[(size_t)i * 32 + m] = (bf)p;
  }
#pragma unroll
  for (int m = 16; m < 32; ++m) phib[(size_t)i * 32 + m] = (bf)0.0f;
}

// ---------- prep: transpose + convert f32 -> bf16 ----------
__global__ __launch_bounds__(256) void k_transpose_cvt(const float* __restrict__ in,
                                                       bf* __restrict__ out, int R, int C) {
  __shared__ float tile[32][33];
  int c0 = blockIdx.x * 32, r0 = blockIdx.y * 32;
  int tx = threadIdx.x, ty = threadIdx.y;  // 32 x 8
#pragma unroll
  for (int i = 0; i < 32; i += 8)
    tile[ty + i][tx] = in[(size_t)(r0 + ty + i) * C + c0 + tx];
  __syncthreads();
#pragma unroll
  for (int i = 0; i < 32; i += 8)
    out[(size_t)(c0 + ty + i) * R + r0 + tx] = (bf)tile[tx][ty + i];
}

// ---------- fused: out = |Phi Phi^T| @ flat ----------
// 64m x 64d tile, grid (64, 8) = 512 blocks (2/CU), 4 waves, double-buffered
// gload_lds staging with one vmcnt-draining barrier + one S barrier per K-step.
__global__ __launch_bounds__(256, 2) void k_gram(const bf* __restrict__ phib,
                                                 const bf* __restrict__ flatT,
                                                 bf* __restrict__ outb) {
  __shared__ __align__(16) char sm[48 * 1024];
  char* phiI = sm;               // [64][128B] swz, 8KB
  char* sT = sm + 8192;          // [64 m][64 j] swz, 8KB
  char* phiJ0 = sm + 16384;      // 2 x 8KB double buffer
  char* ft0 = sm + 32768;        // [64 d][64 j] swz, 2 x 8KB

  const int tid = threadIdx.x;
  const int wave = tid >> 6, lane = tid & 63;
  const int lr = lane & 15, lg = lane >> 4;
  const int wm = wave & 1, wd = wave >> 1;
  const int m0 = blockIdx.x * 64;
  const int n0 = blockIdx.y * 64;

  stage_phi(phib + (size_t)m0 * 32, phiI, wave, lane);
  stage_phi(phib, phiJ0, wave, lane);
  stage_tile<64>(flatT + (size_t)n0 * M_TOT, M_TOT, ft0, wave, lane);
  __syncthreads();

  const bf16x8 a_phi = ldfrag(phiI, wave * 16 + lr, lg * 16);

  f32x4 acc00 = {0.f, 0.f, 0.f, 0.f}, acc01 = acc00, acc10 = acc00, acc11 = acc00;

  constexpr int NT = M_TOT / 64;
  for (int jt = 0; jt < NT; ++jt) {
    const int cur = jt & 1, nxt = cur ^ 1;
    char* phiJc = phiJ0 + cur * 8192;
    char* ftc = ft0 + cur * 8192;
    // S phase: wave w computes S rows [w*16, w*16+16) x 64 j
#pragma unroll
    for (int f = 0; f < 4; ++f) {
      bf16x8 b = ldfrag(phiJc, f * 16 + lr, lg * 16);
      f32x4 sv = __builtin_amdgcn_mfma_f32_16x16x32_bf16(a_phi, b, f32x4{0.f, 0.f, 0.f, 0.f}, 0, 0, 0);
#pragma unroll
      for (int r = 0; r < 4; ++r) {
        int srow = wave * 16 + lg * 4 + r;
        int scol = f * 16 + lr;
        *(bf*)(sT + swz128(srow, scol * 2)) = (bf)fabsf(sv[r]);
      }
    }
    __syncthreads();  // sT visible
    if (jt + 1 < NT) {  // prefetch next tiles; drained at end-of-iter barrier
      stage_phi(phib + (size_t)(jt + 1) * 64 * 32, phiJ0 + nxt * 8192, wave, lane);
      stage_tile<64>(flatT + (size_t)n0 * M_TOT + (jt + 1) * 64, M_TOT, ft0 + nxt * 8192, wave, lane);
    }
    // main MFMA: wave tile 32m x 32d
#pragma unroll
    for (int ks = 0; ks < 2; ++ks) {
      bf16x8 a0 = ldfrag(sT, wm * 32 + lr, (ks * 32 + lg * 8) * 2);
      bf16x8 a1 = ldfrag(sT, wm * 32 + 16 + lr, (ks * 32 + lg * 8) * 2);
      bf16x8 b0 = ldfrag(ftc, wd * 32 + lr, (ks * 32 + lg * 8) * 2);
      bf16x8 b1 = ldfrag(ftc, wd * 32 + 16 + lr, (ks * 32 + lg * 8) * 2);
      acc00 = __builtin_amdgcn_mfma_f32_16x16x32_bf16(a0, b0, acc00, 0, 0, 0);
      acc01 = __builtin_amdgcn_mfma_f32_16x16x32_bf16(a0, b1, acc01, 0, 0, 0);
      acc10 = __builtin_amdgcn_mfma_f32_16x16x32_bf16(a1, b0, acc10, 0, 0, 0);
      acc11 = __builtin_amdgcn_mfma_f32_16x16x32_bf16(a1, b1, acc11, 0, 0, 0);
    }
    __syncthreads();  // frees sT + cur buffers, drains prefetch
  }

#pragma unroll
  for (int i = 0; i < 2; ++i)
#pragma unroll
    for (int f = 0; f < 2; ++f) {
      f32x4 a = (i == 0) ? (f == 0 ? acc00 : acc01) : (f == 0 ? acc10 : acc11);
#pragma unroll
      for (int r = 0; r < 4; ++r) {
        int m = m0 + wm * 32 + i * 16 + lg * 4 + r;
        int d = n0 + wd * 32 + f * 16 + lr;
        outb[(size_t)m * D_EMB + d] = (bf)a[r];
      }
    }
}

// ---------- pipelined bf16 GEMM: C = A[M][K] * BT[N][K]^T + bias ----------
template <int BM, int BN, bool RELU_BF16>
__global__ __launch_bounds__(256, 2) void k_gemm(const bf* __restrict__ A, const bf* __restrict__ BT,
                                                 const float* __restrict__ bias, void* __restrict__ out,
                                                 int M, int N, int K) {
  constexpr int WM = BM / 2, WN = BN / 2;
  constexpr int FM = WM / 16, FN = WN / 16;
  __shared__ __align__(16) char sm[2 * (BM + BN) * 128];
  char* aT0 = sm;                    // 2 x BM*128
  char* bT0 = sm + 2 * BM * 128;     // 2 x BN*128

  const int tid = threadIdx.x;
  const int wave = tid >> 6, lane = tid & 63;
  const int lr = lane & 15, lg = lane >> 4;
  const int wm = wave & 1, wn = wave >> 1;
  const int m0 = blockIdx.x * BM, n0 = blockIdx.y * BN;

  f32x4 acc[FM][FN];
#pragma unroll
  for (int i = 0; i < FM; ++i)
#pragma unroll
    for (int f = 0; f < FN; ++f) acc[i][f] = f32x4{0.f, 0.f, 0.f, 0.f};

  stage_tile<BM>(A + (size_t)m0 * K, K, aT0, wave, lane);
  stage_tile<BN>(BT + (size_t)n0 * K, K, bT0, wave, lane);
  __syncthreads();

  const int NT = K / 64;
  for (int t = 0; t < NT; ++t) {
    const int cur = t & 1, nxt = cur ^ 1;
    char* aTc = aT0 + cur * BM * 128;
    char* bTc = bT0 + cur * BN * 128;
    if (t + 1 < NT) {  // prefetch into other buffer; drained at the barrier
      stage_tile<BM>(A + (size_t)m0 * K + (t + 1) * 64, K, aT0 + nxt * BM * 128, wave, lane);
      stage_tile<BN>(BT + (size_t)n0 * K + (t + 1) * 64, K, bT0 + nxt * BN * 128, wave, lane);
    }
#pragma unroll
    for (int ks = 0; ks < 2; ++ks) {
      bf16x8 a[FM], b[FN];
#pragma unroll
      for (int i = 0; i < FM; ++i) a[i] = ldfrag(aTc, wm * WM + i * 16 + lr, (ks * 32 + lg * 8) * 2);
#pragma unroll
      for (int f = 0; f < FN; ++f) b[f] = ldfrag(bTc, wn * WN + f * 16 + lr, (ks * 32 + lg * 8) * 2);
#pragma unroll
      for (int i = 0; i < FM; ++i)
#pragma unroll
        for (int f = 0; f < FN; ++f)
          acc[i][f] = __builtin_amdgcn_mfma_f32_16x16x32_bf16(a[i], b[f], acc[i][f], 0, 0, 0);
    }
    __syncthreads();
  }

#pragma unroll
  for (int f = 0; f < FN; ++f) {
    int n = n0 + wn * WN + f * 16 + lr;
    float bv = bias[n];
#pragma unroll
    for (int i = 0; i < FM; ++i)
#pragma unroll
      for (int r = 0; r < 4; ++r) {
        int m = m0 + wm * WM + i * 16 + lg * 4 + r;
        float v = acc[i][f][r] + bv;
        if (RELU_BF16) {
          v = v > 0.f ? v : 0.f;
          ((bf*)out)[(size_t)m * N + n] = (bf)v;
        } else {
          ((float*)out)[(size_t)m * N + n] = v;
        }
      }
  }
}

// ---------- workspace layout ----------
constexpr size_t OFF_PHI   = 0;
constexpr size_t OFF_FLATT = OFF_PHI + (size_t)M_TOT * 32 * 2;
constexpr size_t OFF_OUTB  = OFF_FLATT + (size_t)D_EMB * M_TOT * 2;
constexpr size_t OFF_W1T   = OFF_OUTB + (size_t)M_TOT * D_EMB * 2;
constexpr size_t OFF_W2T   = OFF_W1T + (size_t)F_FFN * D_EMB * 2;
constexpr size_t OFF_HB    = OFF_W2T + (size_t)D_EMB * F_FFN * 2;

extern "C" void kernel_launch(void* const* d_in, const int* in_sizes, int n_in,
                              void* d_out, int out_size, void* d_ws, size_t ws_size,
                              hipStream_t stream) {
  const float* x  = (const float*)d_in[0];
  const float* W1 = (const float*)d_in[1];
  const float* b1 = (const float*)d_in[2];
  const float* W2 = (const float*)d_in[3];
  const float* b2 = (const float*)d_in[4];
  float* y = (float*)d_out;
  char* ws = (char*)d_ws;

  bf* phib  = (bf*)(ws + OFF_PHI);
  bf* flatT = (bf*)(ws + OFF_FLATT);
  bf* outb  = (bf*)(ws + OFF_OUTB);
  bf* w1T   = (bf*)(ws + OFF_W1T);
  bf* w2T   = (bf*)(ws + OFF_W2T);
  bf* hb    = (bf*)(ws + OFF_HB);

  k_phi<<<M_TOT / 256, 256, 0, stream>>>(x, phib);
  k_transpose_cvt<<<dim3(D_EMB / 32, M_TOT / 32), dim3(32, 8), 0, stream>>>(x, flatT, M_TOT, D_EMB);
  k_transpose_cvt<<<dim3(F_FFN / 32, D_EMB / 32), dim3(32, 8), 0, stream>>>(W1, w1T, D_EMB, F_FFN);
  k_transpose_cvt<<<dim3(D_EMB / 32, F_FFN / 32), dim3(32, 8), 0, stream>>>(W2, w2T, F_FFN, D_EMB);

  // fused gram @ flat: 64x64 tiles -> 512 blocks (2/CU)
  k_gram<<<dim3(M_TOT / 64, D_EMB / 64), 256, 0, stream>>>(phib, flatT, outb);

  // FFN: 64x128 -> 1024 blocks; 64x64 -> 512 blocks
  k_gemm<64, 128, true ><<<dim3(M_TOT / 64, F_FFN / 128), 256, 0, stream>>>(outb, w1T, b1, (void*)hb, M_TOT, F_FFN, D_EMB);
  k_gemm<64, 64, false><<<dim3(M_TOT / 64, D_EMB / 64), 256, 0, stream>>>(hb, w2T, b2, (void*)y, M_TOT, D_EMB, F_FFN);
}

// Round 4
// 113.791 us; speedup vs baseline: 1.8880x; 1.0484x over previous
//
#include <hip/hip_runtime.h>
#include <hip/hip_bf16.h>
#include <stdint.h>

using bf = __bf16;
typedef __attribute__((ext_vector_type(8))) __bf16 bf16x8;
typedef __attribute__((ext_vector_type(4))) float f32x4;

#define M_TOT 4096
#define D_EMB 512
#define F_FFN 2048

// ---------- async global->LDS, 16B per lane ----------
__device__ __forceinline__ void gload_lds16(const void* g, void* l) {
  __builtin_amdgcn_global_load_lds(
      (const __attribute__((address_space(1))) uint32_t*)g,
      (__attribute__((address_space(3))) uint32_t*)l, 16, 0, 0);
}

// ---------- 128B-row swizzled tiles (K-step 64) ----------
__device__ __forceinline__ int swz128(int row, int b) {
  return row * 128 + (b ^ ((row & 7) << 4));
}
__device__ __forceinline__ bf16x8 ldf128(const char* base, int row, int b) {
  return *(const bf16x8*)(base + swz128(row, b));
}
// linear LDS dest + inverse-swizzled global source (rule #21)
template <int ROWS>
__device__ __forceinline__ void stage_tile(const bf* gsrc, int ld, char* lbase, int wave, int lane) {
  const int rsub = lane >> 3, csub = lane & 7;
#pragma unroll
  for (int i = 0; i < ROWS / 32; ++i) {
    int chunk = wave + i * 4;
    int row = chunk * 8 + rsub;
    int sc = csub ^ (row & 7);
    gload_lds16((const char*)gsrc + (size_t)row * (size_t)(ld * 2) + sc * 16, lbase + chunk * 1024);
  }
}

// ---------- 256B-row swizzled tiles (K-step 128, k_gram) ----------
__device__ __forceinline__ int swz256(int row, int b) {
  return row * 256 + (b ^ ((row & 15) << 4));
}
__device__ __forceinline__ bf16x8 ldf256(const char* base, int row, int b) {
  return *(const bf16x8*)(base + swz256(row, b));
}
// 64 rows x 256B: 16 x 1KB chunks, 4 per wave, lane = (row%4, 16B-col)
__device__ __forceinline__ void stage_ft(const bf* gsrc, char* lbase, int wave, int lane) {
  const int rsub = lane >> 4, csub = lane & 15;
#pragma unroll
  for (int i = 0; i < 4; ++i) {
    int chunk = wave * 4 + i;
    int row = chunk * 4 + rsub;
    int sc = csub ^ (row & 15);
    gload_lds16((const char*)gsrc + (size_t)row * (M_TOT * 2) + sc * 16, lbase + chunk * 1024);
  }
}

// ---------- prep: phi features (rank-16 factorization of the gram) ----------
__global__ __launch_bounds__(256) void k_phi(const float* __restrict__ x, bf* __restrict__ phib) {
  int i = blockIdx.x * 256 + threadIdx.x;
  float c[4], s[4];
#pragma unroll
  for (int k = 0; k < 4; ++k) {
    float f = x[(size_t)i * D_EMB + k] * 0.5f;
    sincosf(f, &s[k], &c[k]);
  }
#pragma unroll
  for (int m = 0; m < 16; ++m) {
    float p = 1.0f;
#pragma unroll
    for (int k = 0; k < 4; ++k) p *= ((m >> k) & 1) ? s[k] : c[k];
    phib[(size_t)i * 32 + m] = (bf)p;
  }
#pragma unroll
  for (int m = 16; m < 32; ++m) phib[(size_t)i * 32 + m] = (bf)0.0f;
}

// ---------- prep: transpose + convert f32 -> bf16 ----------
__global__ __launch_bounds__(256) void k_transpose_cvt(const float* __restrict__ in,
                                                       bf* __restrict__ out, int R, int C) {
  __shared__ float tile[32][33];
  int c0 = blockIdx.x * 32, r0 = blockIdx.y * 32;
  int tx = threadIdx.x, ty = threadIdx.y;
#pragma unroll
  for (int i = 0; i < 32; i += 8)
    tile[ty + i][tx] = in[(size_t)(r0 + ty + i) * C + c0 + tx];
  __syncthreads();
#pragma unroll
  for (int i = 0; i < 32; i += 8)
    out[(size_t)(c0 + ty + i) * R + r0 + tx] = (bf)tile[tx][ty + i];
}

// ---------- fused: out = |Phi Phi^T| @ flat ----------
// 64m x 64d tile, j-step 128, 4 waves, 3-buffer counted-vmcnt pipeline.
// phi A/B fragments straight from global (L2-hot, reg-prefetched 1 iter ahead).
__global__ __launch_bounds__(256, 2) void k_gram(const bf* __restrict__ phib,
                                                 const bf* __restrict__ flatT,
                                                 bf* __restrict__ outb) {
  __shared__ __align__(16) char sm[16384 + 3 * 16384];  // 64KB -> 2 blocks/CU
  char* sT = sm;           // [64 m][128 j] bf16, swz256
  char* ftb = sm + 16384;  // 3 x [64 d][128 j] bf16, swz256

  const int tid = threadIdx.x;
  const int wave = tid >> 6, lane = tid & 63;
  const int lr = lane & 15, lg = lane >> 4;
  const int wm = wave & 1, wd = wave >> 1;

  // XCD swizzle: each XCD owns one d-slab (512 wgs, 8 XCDs, q=64)
  int lin = blockIdx.x + (int)gridDim.x * blockIdx.y;
  int swz = (lin & 7) * 64 + (lin >> 3);
  const int m0 = (swz & 63) * 64;
  const int n0 = (swz >> 6) * 64;

  // prologue: stage ft[0], ft[1]; load phiB(0) + a_phi to regs
  stage_ft(flatT + (size_t)n0 * M_TOT, ftb, wave, lane);
  stage_ft(flatT + (size_t)n0 * M_TOT + 128, ftb + 16384, wave, lane);

  bf16x8 curB[8];
#pragma unroll
  for (int f = 0; f < 8; ++f)
    curB[f] = *(const bf16x8*)(phib + (size_t)(f * 16 + lr) * 32 + lg * 8);
  const bf16x8 a_phi = *(const bf16x8*)(phib + (size_t)(m0 + wave * 16 + lr) * 32 + lg * 8);

  f32x4 acc00 = {0.f, 0.f, 0.f, 0.f}, acc01 = acc00, acc10 = acc00, acc11 = acc00;

  constexpr int NT = M_TOT / 128;  // 32
  for (int t = 0; t < NT; ++t) {
    char* ftc = ftb + (t % 3) * 16384;
    // A: ensure ft[t] landed. newer-than-ft[t] = phiB(t)(8) [+ ft[t+1](4)] -> vmcnt(8) valid for all t.
    asm volatile("s_waitcnt vmcnt(8)" ::: "memory");
    __builtin_amdgcn_s_barrier();

    // prefetch next iter's phi B-fragments (compiler-managed waits)
    bf16x8 nxtB[8];
    if (t + 1 < NT) {
#pragma unroll
      for (int f = 0; f < 8; ++f)
        nxtB[f] = *(const bf16x8*)(phib + (size_t)((t + 1) * 128 + f * 16 + lr) * 32 + lg * 8);
    }
    // stage ft[t+2]
    if (t + 2 < NT)
      stage_ft(flatT + (size_t)n0 * M_TOT + (t + 2) * 128, ftb + ((t + 2) % 3) * 16384, wave, lane);

    // S phase: wave w -> S rows [w*16, w*16+16) x 128 j
#pragma unroll
    for (int f = 0; f < 8; ++f) {
      f32x4 sv = __builtin_amdgcn_mfma_f32_16x16x32_bf16(a_phi, curB[f], f32x4{0.f, 0.f, 0.f, 0.f}, 0, 0, 0);
#pragma unroll
      for (int r = 0; r < 4; ++r)
        *(bf*)(sT + swz256(wave * 16 + lg * 4 + r, (f * 16 + lr) * 2)) = (bf)fabsf(sv[r]);
    }
    asm volatile("s_waitcnt lgkmcnt(0)" ::: "memory");  // S-stores visible
    __builtin_amdgcn_s_barrier();

    // main: 32m x 32d per wave, K=128 in 4 steps
#pragma unroll
    for (int ks = 0; ks < 4; ++ks) {
      bf16x8 a0 = ldf256(sT, wm * 32 + lr, (ks * 32 + lg * 8) * 2);
      bf16x8 a1 = ldf256(sT, wm * 32 + 16 + lr, (ks * 32 + lg * 8) * 2);
      bf16x8 b0 = ldf256(ftc, wd * 32 + lr, (ks * 32 + lg * 8) * 2);
      bf16x8 b1 = ldf256(ftc, wd * 32 + 16 + lr, (ks * 32 + lg * 8) * 2);
      acc00 = __builtin_amdgcn_mfma_f32_16x16x32_bf16(a0, b0, acc00, 0, 0, 0);
      acc01 = __builtin_amdgcn_mfma_f32_16x16x32_bf16(a0, b1, acc01, 0, 0, 0);
      acc10 = __builtin_amdgcn_mfma_f32_16x16x32_bf16(a1, b0, acc10, 0, 0, 0);
      acc11 = __builtin_amdgcn_mfma_f32_16x16x32_bf16(a1, b1, acc11, 0, 0, 0);
    }
#pragma unroll
    for (int f = 0; f < 8; ++f) curB[f] = nxtB[f];
  }

#pragma unroll
  for (int i = 0; i < 2; ++i)
#pragma unroll
    for (int f = 0; f < 2; ++f) {
      f32x4 a = (i == 0) ? (f == 0 ? acc00 : acc01) : (f == 0 ? acc10 : acc11);
#pragma unroll
      for (int r = 0; r < 4; ++r) {
        int m = m0 + wm * 32 + i * 16 + lg * 4 + r;
        int d = n0 + wd * 32 + f * 16 + lr;
        outb[(size_t)m * D_EMB + d] = (bf)a[r];
      }
    }
}

// ---------- bf16 GEMM, 3-buffer counted-vmcnt pipeline ----------
template <int BM, int BN, bool RELU_BF16>
__global__ __launch_bounds__(256, 3) void k_gemm(const bf* __restrict__ A, const bf* __restrict__ BT,
                                                 const float* __restrict__ bias, void* __restrict__ out,
                                                 int M, int N, int K) {
  constexpr int WM = BM / 2, WN = BN / 2;
  constexpr int FM = WM / 16, FN = WN / 16;
  constexpr int BUF = (BM + BN) * 128;
  __shared__ __align__(16) char sm[3 * BUF];

  const int tid = threadIdx.x;
  const int wave = tid >> 6, lane = tid & 63;
  const int lr = lane & 15, lg = lane >> 4;
  const int wm = wave & 1, wn = wave >> 1;
  const int m0 = blockIdx.x * BM, n0 = blockIdx.y * BN;

  f32x4 acc[FM][FN];
#pragma unroll
  for (int i = 0; i < FM; ++i)
#pragma unroll
    for (int f = 0; f < FN; ++f) acc[i][f] = f32x4{0.f, 0.f, 0.f, 0.f};

  // prologue: stage t=0, t=1
  stage_tile<BM>(A + (size_t)m0 * K, K, sm, wave, lane);
  stage_tile<BN>(BT + (size_t)n0 * K, K, sm + BM * 128, wave, lane);
  stage_tile<BM>(A + (size_t)m0 * K + 64, K, sm + BUF, wave, lane);
  stage_tile<BN>(BT + (size_t)n0 * K + 64, K, sm + BUF + BM * 128, wave, lane);

  const int NT = K / 64;
  for (int t = 0; t < NT; ++t) {
    char* aTc = sm + (t % 3) * BUF;
    char* bTc = aTc + BM * 128;
    // newer-than-stage(t) = stage(t+1) (4 loads) mid-loop, 0 at tail
    if (t + 1 < NT) asm volatile("s_waitcnt vmcnt(4)" ::: "memory");
    else            asm volatile("s_waitcnt vmcnt(0)" ::: "memory");
    __builtin_amdgcn_s_barrier();

    if (t + 2 < NT) {
      char* aTn = sm + ((t + 2) % 3) * BUF;
      stage_tile<BM>(A + (size_t)m0 * K + (t + 2) * 64, K, aTn, wave, lane);
      stage_tile<BN>(BT + (size_t)n0 * K + (t + 2) * 64, K, aTn + BM * 128, wave, lane);
    }
#pragma unroll
    for (int ks = 0; ks < 2; ++ks) {
      bf16x8 a[FM], b[FN];
#pragma unroll
      for (int i = 0; i < FM; ++i) a[i] = ldf128(aTc, wm * WM + i * 16 + lr, (ks * 32 + lg * 8) * 2);
#pragma unroll
      for (int f = 0; f < FN; ++f) b[f] = ldf128(bTc, wn * WN + f * 16 + lr, (ks * 32 + lg * 8) * 2);
#pragma unroll
      for (int i = 0; i < FM; ++i)
#pragma unroll
        for (int f = 0; f < FN; ++f)
          acc[i][f] = __builtin_amdgcn_mfma_f32_16x16x32_bf16(a[i], b[f], acc[i][f], 0, 0, 0);
    }
  }

#pragma unroll
  for (int f = 0; f < FN; ++f) {
    int n = n0 + wn * WN + f * 16 + lr;
    float bv = bias[n];
#pragma unroll
    for (int i = 0; i < FM; ++i)
#pragma unroll
      for (int r = 0; r < 4; ++r) {
        int m = m0 + wm * WM + i * 16 + lg * 4 + r;
        float v = acc[i][f][r] + bv;
        if (RELU_BF16) {
          v = v > 0.f ? v : 0.f;
          ((bf*)out)[(size_t)m * N + n] = (bf)v;
        } else {
          ((float*)out)[(size_t)m * N + n] = v;
        }
      }
  }
}

// ---------- workspace layout ----------
constexpr size_t OFF_PHI   = 0;
constexpr size_t OFF_FLATT = OFF_PHI + (size_t)M_TOT * 32 * 2;
constexpr size_t OFF_OUTB  = OFF_FLATT + (size_t)D_EMB * M_TOT * 2;
constexpr size_t OFF_W1T   = OFF_OUTB + (size_t)M_TOT * D_EMB * 2;
constexpr size_t OFF_W2T   = OFF_W1T + (size_t)F_FFN * D_EMB * 2;
constexpr size_t OFF_HB    = OFF_W2T + (size_t)D_EMB * F_FFN * 2;

extern "C" void kernel_launch(void* const* d_in, const int* in_sizes, int n_in,
                              void* d_out, int out_size, void* d_ws, size_t ws_size,
                              hipStream_t stream) {
  const float* x  = (const float*)d_in[0];
  const float* W1 = (const float*)d_in[1];
  const float* b1 = (const float*)d_in[2];
  const float* W2 = (const float*)d_in[3];
  const float* b2 = (const float*)d_in[4];
  float* y = (float*)d_out;
  char* ws = (char*)d_ws;

  bf* phib  = (bf*)(ws + OFF_PHI);
  bf* flatT = (bf*)(ws + OFF_FLATT);
  bf* outb  = (bf*)(ws + OFF_OUTB);
  bf* w1T   = (bf*)(ws + OFF_W1T);
  bf* w2T   = (bf*)(ws + OFF_W2T);
  bf* hb    = (bf*)(ws + OFF_HB);

  k_phi<<<M_TOT / 256, 256, 0, stream>>>(x, phib);
  k_transpose_cvt<<<dim3(D_EMB / 32, M_TOT / 32), dim3(32, 8), 0, stream>>>(x, flatT, M_TOT, D_EMB);
  k_transpose_cvt<<<dim3(F_FFN / 32, D_EMB / 32), dim3(32, 8), 0, stream>>>(W1, w1T, D_EMB, F_FFN);
  k_transpose_cvt<<<dim3(D_EMB / 32, F_FFN / 32), dim3(32, 8), 0, stream>>>(W2, w2T, F_FFN, D_EMB);

  k_gram<<<dim3(M_TOT / 64, D_EMB / 64), 256, 0, stream>>>(phib, flatT, outb);

  k_gemm<64, 64, true ><<<dim3(M_TOT / 64, F_FFN / 64), 256, 0, stream>>>(outb, w1T, b1, (void*)hb, M_TOT, F_FFN, D_EMB);
  k_gemm<64, 64, false><<<dim3(M_TOT / 64, D_EMB / 64), 256, 0, stream>>>(hb, w2T, b2, (void*)y, M_TOT, D_EMB, F_FFN);
}